// Round 15
// baseline (208.924 us; speedup 1.0000x reference)
//
#include <hip/hip_runtime.h>

// Problem: B=1, S=8192, D=4096, D_OUT=4096, FP=256, BITS=4 (MAXQ=15)
// out = mixed @ W^T + bias; mixed = per-row-4bit-quant(x) on q cols, x on fp cols.
// R15 = R14 (207.7us) + i8-loop register diet: 8 stage ptrs -> 2 bases with
// compile-time offsets (saves ~12 VGPR; kills residual 17MB spill), and a1
// ds_reads hoisted into P1 (complete under P1's MFMA shadow; P2 = stage+MFMA
// only). Hazard audit: A(t) region rewritten at P3/P4(t), >=2 barriers after
// the hoisted reads. Peak live ~228 regs < 256.

typedef __attribute__((ext_vector_type(8))) short short8;
typedef __attribute__((ext_vector_type(4))) float f32x4;
typedef __attribute__((ext_vector_type(4))) int int4v;

#define S_ROWS 8192
#define D_IN   4096
#define D_OUTC 4096
#define MAXQF  15.0f

__device__ __forceinline__ unsigned short f2bf(float f) {
  unsigned int u = __float_as_uint(f);
  u += 0x7FFFu + ((u >> 16) & 1u);   // RNE (no NaN in data)
  return (unsigned short)(u >> 16);
}

// ---- kernel 1: fused prep ----
// blocks [0, S_ROWS)               : per-row act quant -> actq i8, xfp bf16, as
// blocks [S_ROWS, S_ROWS+D_OUTC)   : per-row W quant  -> wq i8, wfp bf16, ws
__global__ __launch_bounds__(256) void prep_kernel(const float* __restrict__ x,
                                                   const float* __restrict__ W,
                                                   const int* __restrict__ fp_idx,
                                                   signed char* __restrict__ actq,
                                                   signed char* __restrict__ wq,
                                                   short* __restrict__ xfp,
                                                   short* __restrict__ wfp,
                                                   float* __restrict__ as_,
                                                   float* __restrict__ ws_) {
  const int bid = blockIdx.x;
  const int t = threadIdx.x;
  __shared__ float s_r[4];

  if (bid >= S_ROWS) {
    // ---- W row quant: row = bid - S_ROWS ----
    const int row = bid - S_ROWS;
    const float* wr = W + (size_t)row * D_IN;
    float4 v[4];
    float mx = 0.0f;
#pragma unroll
    for (int i = 0; i < 4; ++i) {
      v[i] = ((const float4*)wr)[i * 256 + t];
      mx = fmaxf(mx, fmaxf(fmaxf(fabsf(v[i].x), fabsf(v[i].y)),
                           fmaxf(fabsf(v[i].z), fabsf(v[i].w))));
    }
#pragma unroll
    for (int d = 32; d > 0; d >>= 1) mx = fmaxf(mx, __shfl_xor(mx, d));
    if ((t & 63) == 0) s_r[t >> 6] = mx;
    __syncthreads();
    mx = fmaxf(fmaxf(s_r[0], s_r[1]), fmaxf(s_r[2], s_r[3]));
    const float wsr = (mx > 0.0f) ? (mx / 127.0f) : 1.0f;

    unsigned int* wrow = (unsigned int*)(wq + (size_t)row * D_IN);
#pragma unroll
    for (int i = 0; i < 4; ++i) {
      const float in[4] = { v[i].x, v[i].y, v[i].z, v[i].w };
      unsigned int pk = 0;
#pragma unroll
      for (int j = 0; j < 4; ++j) {
        int q = (int)fminf(fmaxf(rintf(in[j] / wsr), -127.0f), 127.0f);
        pk |= ((unsigned int)(unsigned char)(signed char)q) << (8 * j);
      }
      wrow[i * 256 + t] = pk;
    }
    wfp[(size_t)row * 256 + t] = (short)f2bf(wr[fp_idx[t]]);
    if (t == 0) ws_[row] = wsr;
    return;
  }

  // ---- activation row quant ----
  __shared__ unsigned char fl[4096];
  ((int4*)fl)[t] = make_int4(0, 0, 0, 0);
  __syncthreads();
  fl[fp_idx[t]] = 1;
  __syncthreads();

  const int row = bid;
  const float* xr = x + (size_t)row * D_IN;

  float4 v[4];
  unsigned int fw[4];
  float mn = 0.0f, mx = 0.0f;   // init at 0 == reference's min(.,0)/max(.,0)
#pragma unroll
  for (int i = 0; i < 4; ++i) {
    const int idx = i * 256 + t;
    v[i] = ((const float4*)xr)[idx];
    fw[i] = ((const unsigned int*)fl)[idx];
    if (!(fw[i] & 0x000000FFu)) { mn = fminf(mn, v[i].x); mx = fmaxf(mx, v[i].x); }
    if (!(fw[i] & 0x0000FF00u)) { mn = fminf(mn, v[i].y); mx = fmaxf(mx, v[i].y); }
    if (!(fw[i] & 0x00FF0000u)) { mn = fminf(mn, v[i].z); mx = fmaxf(mx, v[i].z); }
    if (!(fw[i] & 0xFF000000u)) { mn = fminf(mn, v[i].w); mx = fmaxf(mx, v[i].w); }
  }
  __shared__ float s_mn[4];
#pragma unroll
  for (int d = 32; d > 0; d >>= 1) {
    mn = fminf(mn, __shfl_xor(mn, d));
    mx = fmaxf(mx, __shfl_xor(mx, d));
  }
  if ((t & 63) == 0) { s_mn[t >> 6] = mn; s_r[t >> 6] = mx; }
  __syncthreads();
  mn = fminf(fminf(s_mn[0], s_mn[1]), fminf(s_mn[2], s_mn[3]));
  mx = fmaxf(fmaxf(s_r[0], s_r[1]), fmaxf(s_r[2], s_r[3]));
  if (mn == 0.0f && mx == 0.0f) { mn = -1.0f; mx = 1.0f; }
  const float scale = (mx - mn) / MAXQF;    // exact IEEE div, matches np
  const float zp = rintf(-mn / scale);      // rintf == np round-half-even
  const int zpi = (int)zp;

  unsigned int* arow = (unsigned int*)(actq + (size_t)row * D_IN);
#pragma unroll
  for (int i = 0; i < 4; ++i) {
    const int idx = i * 256 + t;
    const float in[4] = { v[i].x, v[i].y, v[i].z, v[i].w };
    const unsigned int f = fw[i];
    unsigned int pk = 0;
#pragma unroll
    for (int j = 0; j < 4; ++j) {
      int q = (int)fminf(fmaxf(rintf(in[j] / scale) + zp, 0.0f), MAXQF) - zpi;
      if ((f >> (8 * j)) & 0xFFu) q = 0;   // fp col: excluded from i8 sum
      pk |= ((unsigned int)(unsigned char)(signed char)q) << (8 * j);
    }
    arow[idx] = pk;
  }
  xfp[(size_t)row * 256 + t] = (short)f2bf(xr[fp_idx[t]]);
  if (t == 0) as_[row] = scale;
}

// ---------------------------------------------------------------------------
// kernel 2: fused i8 + fp GEMM. i8 = R3 256^2 schedule (a1 reads hoisted to
// P1; 2 stage-pointer bases). fp = single-buffered low-register loop.
// ---------------------------------------------------------------------------

__device__ __forceinline__ void gl2lds16(const void* g, const void* l) {
  __builtin_amdgcn_global_load_lds(
      (const __attribute__((address_space(1))) unsigned int*)g,
      (__attribute__((address_space(3))) unsigned int*)l, 16, 0, 0);
}

#define BARRIER()  asm volatile("s_barrier" ::: "memory")
#define LGKM0()    asm volatile("s_waitcnt lgkmcnt(0)" ::: "memory")

__global__ __launch_bounds__(512, 2) void gemm_i8fp_kernel(
    const signed char* __restrict__ A, const signed char* __restrict__ Bw,
    const short* __restrict__ Afp, const short* __restrict__ Bfp,
    const float* __restrict__ as_, const float* __restrict__ ws_,
    const float* __restrict__ bias, float* __restrict__ C) {
  __shared__ __align__(16) signed char lds[131072];   // 128 KiB
  const int tid = threadIdx.x;
  const int l   = tid & 63;
  const int w   = tid >> 6;
  const int wr  = w >> 2;
  const int wc  = w & 3;
  const int bid = blockIdx.x;
  const int swz = (bid & 7) * 64 + (bid >> 3);
  const int bm  = swz >> 4;
  const int bn  = swz & 15;

  // staging geometry (bytes): chunk = 16B, 8 chunks per 128B row-K-tile
  const int c16  = ((l & 7) ^ (l >> 3)) * 16;
  const int rib0 = (w * 2 + 0) * 8 + (l >> 3);
  const int d0   = (w * 2 + 0) * 1024;
  const int d1   = (w * 2 + 1) * 1024;

  // 2 base pointers; constant strides: rib1 = rib0+8 rows -> +32768B,
  // second 128-row half -> +524288B.
  const signed char* bA = A  + (size_t)(bm * 256 + rib0) * D_IN + c16;
  const signed char* bB = Bw + (size_t)(bn * 256 + rib0) * D_IN + c16;

  // prologue: Kt0 {A0,A1,B0,B1} -> buf0, Kt1 {A0,A1} -> buf1
  gl2lds16(bA, &lds[0 + d0]);                gl2lds16(bA + 32768, &lds[0 + d1]);
  gl2lds16(bA + 524288, &lds[16384 + d0]);   gl2lds16(bA + 557056, &lds[16384 + d1]);
  gl2lds16(bB, &lds[32768 + d0]);            gl2lds16(bB + 32768, &lds[32768 + d1]);
  gl2lds16(bB + 524288, &lds[49152 + d0]);   gl2lds16(bB + 557056, &lds[49152 + d1]);
  gl2lds16(bA + 128, &lds[65536 + d0]);      gl2lds16(bA + 32768 + 128, &lds[65536 + d1]);
  gl2lds16(bA + 524288 + 128, &lds[81920 + d0]);
  gl2lds16(bA + 557056 + 128, &lds[81920 + d1]);
  asm volatile("s_waitcnt vmcnt(4)" ::: "memory");
  BARRIER();

  const signed char* pA = bA + 256;   // A stage base at ktile 2
  const signed char* pB = bB + 128;   // B stage base at ktile 1

  const int ch0  = ((l >> 4) ^ (l & 7)) * 16;
  const int aoff = wr * 16384 + (l & 15) * 128;
  const int boff = 32768 + (wc >> 1) * 16384 + (wc & 1) * 8192 + (l & 15) * 128;

  union AccU {
    int4v ai[8][4];
    f32x4 af[8][4];
  } u;
#pragma unroll
  for (int m = 0; m < 8; ++m)
#pragma unroll
    for (int n = 0; n < 4; ++n) u.ai[m][n] = int4v{0, 0, 0, 0};

  int bo = 0;

  for (int t = 0; t < 32; ++t) {
    const int nxt = bo ^ 65536;
    int4v a0[4][2], a1[4][2], b[2][2];

    // P1: read a[0-3], b[0-1]; stage B0(t+1); hoisted a[4-7] reads under MFMA
#pragma unroll
    for (int m = 0; m < 4; ++m) {
      a0[m][0] = *(const int4v*)&lds[bo + aoff + m * 2048 + ch0];
      a0[m][1] = *(const int4v*)&lds[bo + aoff + m * 2048 + (ch0 ^ 64)];
    }
#pragma unroll
    for (int n = 0; n < 2; ++n) {
      b[n][0] = *(const int4v*)&lds[bo + boff + n * 2048 + ch0];
      b[n][1] = *(const int4v*)&lds[bo + boff + n * 2048 + (ch0 ^ 64)];
    }
    if (t < 31) { gl2lds16(pB, &lds[nxt + 32768 + d0]);
                  gl2lds16(pB + 32768, &lds[nxt + 32768 + d1]); }
    asm volatile("s_waitcnt lgkmcnt(8)" ::: "memory");
    BARRIER();
    LGKM0();
    // hoisted a1 reads: issue now, complete under P1's MFMA cluster
#pragma unroll
    for (int m = 0; m < 4; ++m) {
      a1[m][0] = *(const int4v*)&lds[bo + aoff + (m + 4) * 2048 + ch0];
      a1[m][1] = *(const int4v*)&lds[bo + aoff + (m + 4) * 2048 + (ch0 ^ 64)];
    }
    __builtin_amdgcn_s_setprio(1);
#pragma unroll
    for (int m = 0; m < 4; ++m)
#pragma unroll
      for (int n = 0; n < 2; ++n) {
        u.ai[m][n] = __builtin_amdgcn_mfma_i32_16x16x64_i8(a0[m][0], b[n][0], u.ai[m][n], 0, 0, 0);
        u.ai[m][n] = __builtin_amdgcn_mfma_i32_16x16x64_i8(a0[m][1], b[n][1], u.ai[m][n], 0, 0, 0);
      }
    __builtin_amdgcn_s_setprio(0);
    BARRIER();

    // P2: stage B1(t+1); MFMA a1 x b01 (reads already in flight/complete)
    if (t < 31) { gl2lds16(pB + 524288, &lds[nxt + 49152 + d0]);
                  gl2lds16(pB + 557056, &lds[nxt + 49152 + d1]); }
    BARRIER();
    LGKM0();
    __builtin_amdgcn_s_setprio(1);
#pragma unroll
    for (int m = 0; m < 4; ++m)
#pragma unroll
      for (int n = 0; n < 2; ++n) {
        u.ai[m + 4][n] = __builtin_amdgcn_mfma_i32_16x16x64_i8(a1[m][0], b[n][0], u.ai[m + 4][n], 0, 0, 0);
        u.ai[m + 4][n] = __builtin_amdgcn_mfma_i32_16x16x64_i8(a1[m][1], b[n][1], u.ai[m + 4][n], 0, 0, 0);
      }
    __builtin_amdgcn_s_setprio(0);
    BARRIER();

    // P3: read b[2-3]; stage A0(t+2)
#pragma unroll
    for (int n = 0; n < 2; ++n) {
      b[n][0] = *(const int4v*)&lds[bo + boff + (n + 2) * 2048 + ch0];
      b[n][1] = *(const int4v*)&lds[bo + boff + (n + 2) * 2048 + (ch0 ^ 64)];
    }
    if (t < 30) { gl2lds16(pA, &lds[bo + 0 + d0]);
                  gl2lds16(pA + 32768, &lds[bo + 0 + d1]); }
    BARRIER();
    LGKM0();
    __builtin_amdgcn_s_setprio(1);
#pragma unroll
    for (int m = 0; m < 4; ++m)
#pragma unroll
      for (int n = 0; n < 2; ++n) {
        u.ai[m + 4][n + 2] = __builtin_amdgcn_mfma_i32_16x16x64_i8(a1[m][0], b[n][0], u.ai[m + 4][n + 2], 0, 0, 0);
        u.ai[m + 4][n + 2] = __builtin_amdgcn_mfma_i32_16x16x64_i8(a1[m][1], b[n][1], u.ai[m + 4][n + 2], 0, 0, 0);
      }
    __builtin_amdgcn_s_setprio(0);
    BARRIER();

    // P4: stage A1(t+2); reg-only MFMA; counted vmcnt
    if (t < 30) { gl2lds16(pA + 524288, &lds[bo + 16384 + d0]);
                  gl2lds16(pA + 557056, &lds[bo + 16384 + d1]); }
    BARRIER();
    __builtin_amdgcn_s_setprio(1);
#pragma unroll
    for (int m = 0; m < 4; ++m)
#pragma unroll
      for (int n = 0; n < 2; ++n) {
        u.ai[m][n + 2] = __builtin_amdgcn_mfma_i32_16x16x64_i8(a0[m][0], b[n][0], u.ai[m][n + 2], 0, 0, 0);
        u.ai[m][n + 2] = __builtin_amdgcn_mfma_i32_16x16x64_i8(a0[m][1], b[n][1], u.ai[m][n + 2], 0, 0, 0);
      }
    __builtin_amdgcn_s_setprio(0);
    if (t < 30) { asm volatile("s_waitcnt vmcnt(4)" ::: "memory"); }
    else        { asm volatile("s_waitcnt vmcnt(0)" ::: "memory"); }
    BARRIER();

    pA += 128; pB += 128;
    bo = nxt;
  }

  // ---- in-place convert: u.af = as[row]*ws[col]*u.ai ----
  const int row0 = bm * 256 + wr * 128 + ((l >> 4) << 2);
  const int col0 = bn * 256 + wc * 64 + (l & 15);
#pragma unroll
  for (int m = 0; m < 8; ++m)
#pragma unroll
    for (int n = 0; n < 4; ++n) {
      const float wsv = ws_[col0 + n * 16];
      f32x4 tmp;
#pragma unroll
      for (int r = 0; r < 4; ++r)
        tmp[r] = (float)u.ai[m][n][r] * (as_[row0 + m * 16 + r] * wsv);
      u.af[m][n] = tmp;
    }

  // ---- fp phase: u.af += xfp @ wfp^T (K=256, 4 K-tiles, single-buffered,
  //      low-register: 2 base ptrs + constant strides, b hoisted) ----
  short* sh = (short*)lds;
  const int c16s = ((l & 7) ^ (l >> 3)) * 8;   // shorts
  const short* fA = Afp + (size_t)(bm * 256 + rib0) * 256 + c16s;
  const short* fB = Bfp + (size_t)(bn * 256 + rib0) * 256 + c16s;
  const int ds0 = (w * 2 + 0) * 512;   // short-granular LDS dest
  const int ds1 = (w * 2 + 1) * 512;

  const int ch0s  = ((l >> 4) ^ (l & 7)) * 8;
  const int aoffs = wr * 8192 + (l & 15) * 64;
  const int boffs = 16384 + (wc >> 1) * 8192 + (wc & 1) * 4096 + (l & 15) * 64;

  for (int t = 0; t < 4; ++t) {
    const int ko = t * 64;
    // stage A0,A1,B0,B1 (rib1 = rib0+8 rows -> +2048; half = 128 rows -> +32768)
    gl2lds16(fA + ko,         &sh[0 + ds0]);
    gl2lds16(fA + 2048 + ko,  &sh[0 + ds1]);
    gl2lds16(fA + 32768 + ko, &sh[8192 + ds0]);
    gl2lds16(fA + 34816 + ko, &sh[8192 + ds1]);
    gl2lds16(fB + ko,         &sh[16384 + ds0]);
    gl2lds16(fB + 2048 + ko,  &sh[16384 + ds1]);
    gl2lds16(fB + 32768 + ko, &sh[24576 + ds0]);
    gl2lds16(fB + 34816 + ko, &sh[24576 + ds1]);
    asm volatile("s_waitcnt vmcnt(0)" ::: "memory");
    BARRIER();

    short8 bf[4][2];
#pragma unroll
    for (int n = 0; n < 4; ++n) {
      bf[n][0] = *(const short8*)&sh[boffs + n * 1024 + ch0s];
      bf[n][1] = *(const short8*)&sh[boffs + n * 1024 + (ch0s ^ 32)];
    }
#pragma unroll
    for (int mi = 0; mi < 8; ++mi) {
      short8 av0 = *(const short8*)&sh[aoffs + mi * 1024 + ch0s];
      short8 av1 = *(const short8*)&sh[aoffs + mi * 1024 + (ch0s ^ 32)];
#pragma unroll
      for (int n = 0; n < 4; ++n) {
        u.af[mi][n] = __builtin_amdgcn_mfma_f32_16x16x32_bf16(av0, bf[n][0], u.af[mi][n], 0, 0, 0);
        u.af[mi][n] = __builtin_amdgcn_mfma_f32_16x16x32_bf16(av1, bf[n][1], u.af[mi][n], 0, 0, 0);
      }
    }
    LGKM0();
    BARRIER();   // write-after-read: all LDS reads done before next stage
  }

  // ---- epilogue: C = u.af + bias ----
#pragma unroll
  for (int m = 0; m < 8; ++m)
#pragma unroll
    for (int n = 0; n < 4; ++n) {
      const int col = col0 + n * 16;
      const float bv = bias[col];
#pragma unroll
      for (int r = 0; r < 4; ++r)
        C[(size_t)(row0 + m * 16 + r) * D_OUTC + col] = u.af[m][n][r] + bv;
    }
}

extern "C" void kernel_launch(void* const* d_in, const int* in_sizes, int n_in,
                              void* d_out, int out_size, void* d_ws, size_t ws_size,
                              hipStream_t stream) {
  const float* x    = (const float*)d_in[0];
  const float* W    = (const float*)d_in[1];
  const float* bias = (const float*)d_in[2];
  const int* fp_idx = (const int*)d_in[4];   // int32 (harness demotes int64)

  char* ws = (char*)d_ws;
  signed char* actq = (signed char*)ws;                               // 32 MB
  signed char* wq   = (signed char*)(ws + (32u << 20));               // 16 MB
  short* xfp        = (short*)(ws + (48u << 20));                     // 4 MB
  short* wfp        = (short*)(ws + (52u << 20));                     // 2 MB
  float* as_        = (float*)(ws + (54u << 20));                     // 32 KB
  float* ws_        = (float*)(ws + (54u << 20) + (64u << 10));       // 16 KB
  float* out = (float*)d_out;

  prep_kernel<<<S_ROWS + D_OUTC, 256, 0, stream>>>(x, W, fp_idx, actq, wq,
                                                   xfp, wfp, as_, ws_);
  gemm_i8fp_kernel<<<512, 512, 0, stream>>>(actq, wq, xfp, wfp, as_, ws_,
                                            bias, out);
}

// Round 16
// 207.277 us; speedup vs baseline: 1.0079x; 1.0079x over previous
//
#include <hip/hip_runtime.h>

// Problem: B=1, S=8192, D=4096, D_OUT=4096, FP=256, BITS=4 (MAXQ=15)
// out = mixed @ W^T + bias; mixed = per-row-4bit-quant(x) on q cols, x on fp cols.
// FINAL (= R14, session best 207.7us):
//   prep: per-row exact-fp32 quant -> act_int i8 (q-zp, exact) + per-row scale;
//         W -> per-row i8; fp cols gathered to bf16 xfp/wfp. HBM-roofline.
//   gemm: fused i8 (R3 256^2 schedule, 32 K-tiles, mfma_i32_16x16x64_i8,
//         XOR-swizzled LDS, counted vmcnt(4), setprio) -> in-place scale
//         (union) -> low-register single-buffered bf16 fp phase (K=256)
//         -> C = acc + bias. absmax 0.078 (thr 0.146).
// Ledger: R4 stage-clustering, R5 read-hoist(spill), R6 L2 remap, R7 unroll
// (I-cache), R9 32x32 MFMA (bank conflicts), R15 reg-diet/hoist: all
// regressed or neutral -> this structure is the verified local optimum.

typedef __attribute__((ext_vector_type(8))) short short8;
typedef __attribute__((ext_vector_type(4))) float f32x4;
typedef __attribute__((ext_vector_type(4))) int int4v;

#define S_ROWS 8192
#define D_IN   4096
#define D_OUTC 4096
#define MAXQF  15.0f

__device__ __forceinline__ unsigned short f2bf(float f) {
  unsigned int u = __float_as_uint(f);
  u += 0x7FFFu + ((u >> 16) & 1u);   // RNE (no NaN in data)
  return (unsigned short)(u >> 16);
}

// ---- kernel 1: fused prep ----
// blocks [0, S_ROWS)               : per-row act quant -> actq i8, xfp bf16, as
// blocks [S_ROWS, S_ROWS+D_OUTC)   : per-row W quant  -> wq i8, wfp bf16, ws
__global__ __launch_bounds__(256) void prep_kernel(const float* __restrict__ x,
                                                   const float* __restrict__ W,
                                                   const int* __restrict__ fp_idx,
                                                   signed char* __restrict__ actq,
                                                   signed char* __restrict__ wq,
                                                   short* __restrict__ xfp,
                                                   short* __restrict__ wfp,
                                                   float* __restrict__ as_,
                                                   float* __restrict__ ws_) {
  const int bid = blockIdx.x;
  const int t = threadIdx.x;
  __shared__ float s_r[4];

  if (bid >= S_ROWS) {
    // ---- W row quant: row = bid - S_ROWS ----
    const int row = bid - S_ROWS;
    const float* wr = W + (size_t)row * D_IN;
    float4 v[4];
    float mx = 0.0f;
#pragma unroll
    for (int i = 0; i < 4; ++i) {
      v[i] = ((const float4*)wr)[i * 256 + t];
      mx = fmaxf(mx, fmaxf(fmaxf(fabsf(v[i].x), fabsf(v[i].y)),
                           fmaxf(fabsf(v[i].z), fabsf(v[i].w))));
    }
#pragma unroll
    for (int d = 32; d > 0; d >>= 1) mx = fmaxf(mx, __shfl_xor(mx, d));
    if ((t & 63) == 0) s_r[t >> 6] = mx;
    __syncthreads();
    mx = fmaxf(fmaxf(s_r[0], s_r[1]), fmaxf(s_r[2], s_r[3]));
    const float wsr = (mx > 0.0f) ? (mx / 127.0f) : 1.0f;

    unsigned int* wrow = (unsigned int*)(wq + (size_t)row * D_IN);
#pragma unroll
    for (int i = 0; i < 4; ++i) {
      const float in[4] = { v[i].x, v[i].y, v[i].z, v[i].w };
      unsigned int pk = 0;
#pragma unroll
      for (int j = 0; j < 4; ++j) {
        int q = (int)fminf(fmaxf(rintf(in[j] / wsr), -127.0f), 127.0f);
        pk |= ((unsigned int)(unsigned char)(signed char)q) << (8 * j);
      }
      wrow[i * 256 + t] = pk;
    }
    wfp[(size_t)row * 256 + t] = (short)f2bf(wr[fp_idx[t]]);
    if (t == 0) ws_[row] = wsr;
    return;
  }

  // ---- activation row quant ----
  __shared__ unsigned char fl[4096];
  ((int4*)fl)[t] = make_int4(0, 0, 0, 0);
  __syncthreads();
  fl[fp_idx[t]] = 1;
  __syncthreads();

  const int row = bid;
  const float* xr = x + (size_t)row * D_IN;

  float4 v[4];
  unsigned int fw[4];
  float mn = 0.0f, mx = 0.0f;   // init at 0 == reference's min(.,0)/max(.,0)
#pragma unroll
  for (int i = 0; i < 4; ++i) {
    const int idx = i * 256 + t;
    v[i] = ((const float4*)xr)[idx];
    fw[i] = ((const unsigned int*)fl)[idx];
    if (!(fw[i] & 0x000000FFu)) { mn = fminf(mn, v[i].x); mx = fmaxf(mx, v[i].x); }
    if (!(fw[i] & 0x0000FF00u)) { mn = fminf(mn, v[i].y); mx = fmaxf(mx, v[i].y); }
    if (!(fw[i] & 0x00FF0000u)) { mn = fminf(mn, v[i].z); mx = fmaxf(mx, v[i].z); }
    if (!(fw[i] & 0xFF000000u)) { mn = fminf(mn, v[i].w); mx = fmaxf(mx, v[i].w); }
  }
  __shared__ float s_mn[4];
#pragma unroll
  for (int d = 32; d > 0; d >>= 1) {
    mn = fminf(mn, __shfl_xor(mn, d));
    mx = fmaxf(mx, __shfl_xor(mx, d));
  }
  if ((t & 63) == 0) { s_mn[t >> 6] = mn; s_r[t >> 6] = mx; }
  __syncthreads();
  mn = fminf(fminf(s_mn[0], s_mn[1]), fminf(s_mn[2], s_mn[3]));
  mx = fmaxf(fmaxf(s_r[0], s_r[1]), fmaxf(s_r[2], s_r[3]));
  if (mn == 0.0f && mx == 0.0f) { mn = -1.0f; mx = 1.0f; }
  const float scale = (mx - mn) / MAXQF;    // exact IEEE div, matches np
  const float zp = rintf(-mn / scale);      // rintf == np round-half-even
  const int zpi = (int)zp;

  unsigned int* arow = (unsigned int*)(actq + (size_t)row * D_IN);
#pragma unroll
  for (int i = 0; i < 4; ++i) {
    const int idx = i * 256 + t;
    const float in[4] = { v[i].x, v[i].y, v[i].z, v[i].w };
    const unsigned int f = fw[i];
    unsigned int pk = 0;
#pragma unroll
    for (int j = 0; j < 4; ++j) {
      int q = (int)fminf(fmaxf(rintf(in[j] / scale) + zp, 0.0f), MAXQF) - zpi;
      if ((f >> (8 * j)) & 0xFFu) q = 0;   // fp col: excluded from i8 sum
      pk |= ((unsigned int)(unsigned char)(signed char)q) << (8 * j);
    }
    arow[idx] = pk;
  }
  xfp[(size_t)row * 256 + t] = (short)f2bf(xr[fp_idx[t]]);
  if (t == 0) as_[row] = scale;
}

// ---------------------------------------------------------------------------
// kernel 2: fused i8 + fp GEMM. i8 = R3 256^2 schedule (proven).
// fp = single-buffered low-register loop.
// ---------------------------------------------------------------------------

__device__ __forceinline__ void gl2lds16(const void* g, const void* l) {
  __builtin_amdgcn_global_load_lds(
      (const __attribute__((address_space(1))) unsigned int*)g,
      (__attribute__((address_space(3))) unsigned int*)l, 16, 0, 0);
}

#define BARRIER()  asm volatile("s_barrier" ::: "memory")
#define LGKM0()    asm volatile("s_waitcnt lgkmcnt(0)" ::: "memory")

__global__ __launch_bounds__(512, 2) void gemm_i8fp_kernel(
    const signed char* __restrict__ A, const signed char* __restrict__ Bw,
    const short* __restrict__ Afp, const short* __restrict__ Bfp,
    const float* __restrict__ as_, const float* __restrict__ ws_,
    const float* __restrict__ bias, float* __restrict__ C) {
  __shared__ __align__(16) signed char lds[131072];   // 128 KiB
  const int tid = threadIdx.x;
  const int l   = tid & 63;
  const int w   = tid >> 6;
  const int wr  = w >> 2;
  const int wc  = w & 3;
  const int bid = blockIdx.x;
  const int swz = (bid & 7) * 64 + (bid >> 3);
  const int bm  = swz >> 4;
  const int bn  = swz & 15;

  // staging geometry (bytes): chunk = 16B, 8 chunks per 128B row-K-tile
  const int c16  = ((l & 7) ^ (l >> 3)) * 16;
  const int rib0 = (w * 2 + 0) * 8 + (l >> 3);
  const int rib1 = (w * 2 + 1) * 8 + (l >> 3);
  const int d0   = (w * 2 + 0) * 1024;
  const int d1   = (w * 2 + 1) * 1024;

  const signed char* bA00 = A  + (size_t)(bm * 256 +   0 + rib0) * D_IN + c16;
  const signed char* bA01 = A  + (size_t)(bm * 256 +   0 + rib1) * D_IN + c16;
  const signed char* bA10 = A  + (size_t)(bm * 256 + 128 + rib0) * D_IN + c16;
  const signed char* bA11 = A  + (size_t)(bm * 256 + 128 + rib1) * D_IN + c16;
  const signed char* bB00 = Bw + (size_t)(bn * 256 +   0 + rib0) * D_IN + c16;
  const signed char* bB01 = Bw + (size_t)(bn * 256 +   0 + rib1) * D_IN + c16;
  const signed char* bB10 = Bw + (size_t)(bn * 256 + 128 + rib0) * D_IN + c16;
  const signed char* bB11 = Bw + (size_t)(bn * 256 + 128 + rib1) * D_IN + c16;

  // prologue: Kt0 {A0,A1,B0,B1} -> buf0, Kt1 {A0,A1} -> buf1
  gl2lds16(bA00, &lds[0 + d0]);           gl2lds16(bA01, &lds[0 + d1]);
  gl2lds16(bA10, &lds[16384 + d0]);       gl2lds16(bA11, &lds[16384 + d1]);
  gl2lds16(bB00, &lds[32768 + d0]);       gl2lds16(bB01, &lds[32768 + d1]);
  gl2lds16(bB10, &lds[49152 + d0]);       gl2lds16(bB11, &lds[49152 + d1]);
  gl2lds16(bA00 + 128, &lds[65536 + d0]); gl2lds16(bA01 + 128, &lds[65536 + d1]);
  gl2lds16(bA10 + 128, &lds[81920 + d0]); gl2lds16(bA11 + 128, &lds[81920 + d1]);
  asm volatile("s_waitcnt vmcnt(4)" ::: "memory");
  BARRIER();

  const signed char* pA00 = bA00 + 256; const signed char* pA01 = bA01 + 256;
  const signed char* pA10 = bA10 + 256; const signed char* pA11 = bA11 + 256;
  const signed char* pB00 = bB00 + 128; const signed char* pB01 = bB01 + 128;
  const signed char* pB10 = bB10 + 128; const signed char* pB11 = bB11 + 128;

  const int ch0  = ((l >> 4) ^ (l & 7)) * 16;
  const int aoff = wr * 16384 + (l & 15) * 128;
  const int boff = 32768 + (wc >> 1) * 16384 + (wc & 1) * 8192 + (l & 15) * 128;

  union AccU {
    int4v ai[8][4];
    f32x4 af[8][4];
  } u;
#pragma unroll
  for (int m = 0; m < 8; ++m)
#pragma unroll
    for (int n = 0; n < 4; ++n) u.ai[m][n] = int4v{0, 0, 0, 0};

  int bo = 0;

  for (int t = 0; t < 32; ++t) {
    const int nxt = bo ^ 65536;
    int4v a0[4][2], a1[4][2], b[2][2];

    // P1: read a[0-3], b[0-1]; stage B0(t+1)
#pragma unroll
    for (int m = 0; m < 4; ++m) {
      a0[m][0] = *(const int4v*)&lds[bo + aoff + m * 2048 + ch0];
      a0[m][1] = *(const int4v*)&lds[bo + aoff + m * 2048 + (ch0 ^ 64)];
    }
#pragma unroll
    for (int n = 0; n < 2; ++n) {
      b[n][0] = *(const int4v*)&lds[bo + boff + n * 2048 + ch0];
      b[n][1] = *(const int4v*)&lds[bo + boff + n * 2048 + (ch0 ^ 64)];
    }
    if (t < 31) { gl2lds16(pB00, &lds[nxt + 32768 + d0]);
                  gl2lds16(pB01, &lds[nxt + 32768 + d1]); }
    asm volatile("s_waitcnt lgkmcnt(8)" ::: "memory");
    BARRIER();
    LGKM0();
    __builtin_amdgcn_s_setprio(1);
#pragma unroll
    for (int m = 0; m < 4; ++m)
#pragma unroll
      for (int n = 0; n < 2; ++n) {
        u.ai[m][n] = __builtin_amdgcn_mfma_i32_16x16x64_i8(a0[m][0], b[n][0], u.ai[m][n], 0, 0, 0);
        u.ai[m][n] = __builtin_amdgcn_mfma_i32_16x16x64_i8(a0[m][1], b[n][1], u.ai[m][n], 0, 0, 0);
      }
    __builtin_amdgcn_s_setprio(0);
    BARRIER();

    // P2: read a[4-7]; stage B1(t+1)
#pragma unroll
    for (int m = 0; m < 4; ++m) {
      a1[m][0] = *(const int4v*)&lds[bo + aoff + (m + 4) * 2048 + ch0];
      a1[m][1] = *(const int4v*)&lds[bo + aoff + (m + 4) * 2048 + (ch0 ^ 64)];
    }
    if (t < 31) { gl2lds16(pB10, &lds[nxt + 49152 + d0]);
                  gl2lds16(pB11, &lds[nxt + 49152 + d1]); }
    BARRIER();
    LGKM0();
    __builtin_amdgcn_s_setprio(1);
#pragma unroll
    for (int m = 0; m < 4; ++m)
#pragma unroll
      for (int n = 0; n < 2; ++n) {
        u.ai[m + 4][n] = __builtin_amdgcn_mfma_i32_16x16x64_i8(a1[m][0], b[n][0], u.ai[m + 4][n], 0, 0, 0);
        u.ai[m + 4][n] = __builtin_amdgcn_mfma_i32_16x16x64_i8(a1[m][1], b[n][1], u.ai[m + 4][n], 0, 0, 0);
      }
    __builtin_amdgcn_s_setprio(0);
    BARRIER();

    // P3: read b[2-3]; stage A0(t+2)
#pragma unroll
    for (int n = 0; n < 2; ++n) {
      b[n][0] = *(const int4v*)&lds[bo + boff + (n + 2) * 2048 + ch0];
      b[n][1] = *(const int4v*)&lds[bo + boff + (n + 2) * 2048 + (ch0 ^ 64)];
    }
    if (t < 30) { gl2lds16(pA00, &lds[bo + 0 + d0]);
                  gl2lds16(pA01, &lds[bo + 0 + d1]); }
    BARRIER();
    LGKM0();
    __builtin_amdgcn_s_setprio(1);
#pragma unroll
    for (int m = 0; m < 4; ++m)
#pragma unroll
      for (int n = 0; n < 2; ++n) {
        u.ai[m + 4][n + 2] = __builtin_amdgcn_mfma_i32_16x16x64_i8(a1[m][0], b[n][0], u.ai[m + 4][n + 2], 0, 0, 0);
        u.ai[m + 4][n + 2] = __builtin_amdgcn_mfma_i32_16x16x64_i8(a1[m][1], b[n][1], u.ai[m + 4][n + 2], 0, 0, 0);
      }
    __builtin_amdgcn_s_setprio(0);
    BARRIER();

    // P4: stage A1(t+2); reg-only MFMA; counted vmcnt
    if (t < 30) { gl2lds16(pA10, &lds[bo + 16384 + d0]);
                  gl2lds16(pA11, &lds[bo + 16384 + d1]); }
    BARRIER();
    __builtin_amdgcn_s_setprio(1);
#pragma unroll
    for (int m = 0; m < 4; ++m)
#pragma unroll
      for (int n = 0; n < 2; ++n) {
        u.ai[m][n + 2] = __builtin_amdgcn_mfma_i32_16x16x64_i8(a0[m][0], b[n][0], u.ai[m][n + 2], 0, 0, 0);
        u.ai[m][n + 2] = __builtin_amdgcn_mfma_i32_16x16x64_i8(a0[m][1], b[n][1], u.ai[m][n + 2], 0, 0, 0);
      }
    __builtin_amdgcn_s_setprio(0);
    if (t < 30) { asm volatile("s_waitcnt vmcnt(4)" ::: "memory"); }
    else        { asm volatile("s_waitcnt vmcnt(0)" ::: "memory"); }
    BARRIER();

    pA00 += 128; pA01 += 128; pA10 += 128; pA11 += 128;
    pB00 += 128; pB01 += 128; pB10 += 128; pB11 += 128;
    bo = nxt;
  }

  // ---- in-place convert: u.af = as[row]*ws[col]*u.ai ----
  const int row0 = bm * 256 + wr * 128 + ((l >> 4) << 2);
  const int col0 = bn * 256 + wc * 64 + (l & 15);
#pragma unroll
  for (int m = 0; m < 8; ++m)
#pragma unroll
    for (int n = 0; n < 4; ++n) {
      const float wsv = ws_[col0 + n * 16];
      f32x4 tmp;
#pragma unroll
      for (int r = 0; r < 4; ++r)
        tmp[r] = (float)u.ai[m][n][r] * (as_[row0 + m * 16 + r] * wsv);
      u.af[m][n] = tmp;
    }

  // ---- fp phase: u.af += xfp @ wfp^T (K=256, 4 K-tiles, single-buffered,
  //      low-register: 2 base ptrs + constant strides, b hoisted) ----
  short* sh = (short*)lds;
  const int c16s = ((l & 7) ^ (l >> 3)) * 8;   // shorts
  const short* fA = Afp + (size_t)(bm * 256 + rib0) * 256 + c16s;
  const short* fB = Bfp + (size_t)(bn * 256 + rib0) * 256 + c16s;
  const int ds0 = (w * 2 + 0) * 512;   // short-granular LDS dest
  const int ds1 = (w * 2 + 1) * 512;

  const int ch0s  = ((l >> 4) ^ (l & 7)) * 8;
  const int aoffs = wr * 8192 + (l & 15) * 64;
  const int boffs = 16384 + (wc >> 1) * 8192 + (wc & 1) * 4096 + (l & 15) * 64;

  for (int t = 0; t < 4; ++t) {
    const int ko = t * 64;
    // stage A0,A1,B0,B1 (rib1 = rib0+8 rows -> +2048; half = 128 rows -> +32768)
    gl2lds16(fA + ko,         &sh[0 + ds0]);
    gl2lds16(fA + 2048 + ko,  &sh[0 + ds1]);
    gl2lds16(fA + 32768 + ko, &sh[8192 + ds0]);
    gl2lds16(fA + 34816 + ko, &sh[8192 + ds1]);
    gl2lds16(fB + ko,         &sh[16384 + ds0]);
    gl2lds16(fB + 2048 + ko,  &sh[16384 + ds1]);
    gl2lds16(fB + 32768 + ko, &sh[24576 + ds0]);
    gl2lds16(fB + 34816 + ko, &sh[24576 + ds1]);
    asm volatile("s_waitcnt vmcnt(0)" ::: "memory");
    BARRIER();

    short8 bf[4][2];
#pragma unroll
    for (int n = 0; n < 4; ++n) {
      bf[n][0] = *(const short8*)&sh[boffs + n * 1024 + ch0s];
      bf[n][1] = *(const short8*)&sh[boffs + n * 1024 + (ch0s ^ 32)];
    }
#pragma unroll
    for (int mi = 0; mi < 8; ++mi) {
      short8 av0 = *(const short8*)&sh[aoffs + mi * 1024 + ch0s];
      short8 av1 = *(const short8*)&sh[aoffs + mi * 1024 + (ch0s ^ 32)];
#pragma unroll
      for (int n = 0; n < 4; ++n) {
        u.af[mi][n] = __builtin_amdgcn_mfma_f32_16x16x32_bf16(av0, bf[n][0], u.af[mi][n], 0, 0, 0);
        u.af[mi][n] = __builtin_amdgcn_mfma_f32_16x16x32_bf16(av1, bf[n][1], u.af[mi][n], 0, 0, 0);
      }
    }
    LGKM0();
    BARRIER();   // write-after-read: all LDS reads done before next stage
  }

  // ---- epilogue: C = u.af + bias ----
#pragma unroll
  for (int m = 0; m < 8; ++m)
#pragma unroll
    for (int n = 0; n < 4; ++n) {
      const int col = col0 + n * 16;
      const float bv = bias[col];
#pragma unroll
      for (int r = 0; r < 4; ++r)
        C[(size_t)(row0 + m * 16 + r) * D_OUTC + col] = u.af[m][n][r] + bv;
    }
}

extern "C" void kernel_launch(void* const* d_in, const int* in_sizes, int n_in,
                              void* d_out, int out_size, void* d_ws, size_t ws_size,
                              hipStream_t stream) {
  const float* x    = (const float*)d_in[0];
  const float* W    = (const float*)d_in[1];
  const float* bias = (const float*)d_in[2];
  const int* fp_idx = (const int*)d_in[4];   // int32 (harness demotes int64)

  char* ws = (char*)d_ws;
  signed char* actq = (signed char*)ws;                               // 32 MB
  signed char* wq   = (signed char*)(ws + (32u << 20));               // 16 MB
  short* xfp        = (short*)(ws + (48u << 20));                     // 4 MB
  short* wfp        = (short*)(ws + (52u << 20));                     // 2 MB
  float* as_        = (float*)(ws + (54u << 20));                     // 32 KB
  float* ws_        = (float*)(ws + (54u << 20) + (64u << 10));       // 16 KB
  float* out = (float*)d_out;

  prep_kernel<<<S_ROWS + D_OUTC, 256, 0, stream>>>(x, W, fp_idx, actq, wq,
                                                   xfp, wfp, as_, ws_);
  gemm_i8fp_kernel<<<512, 512, 0, stream>>>(actq, wq, xfp, wfp, as_, ws_,
                                            bias, out);
}